// Round 8
// baseline (122.309 us; speedup 1.0000x reference)
//
#include <hip/hip_runtime.h>
#include <math.h>

#define C_NUM 1000
#define M_MODES 10
#define CMTOT (C_NUM * M_MODES)   // 10000
#define D_FEAT 128
#define N_BATCH 1024

typedef _Float16 h16;
typedef h16 h16x2 __attribute__((ext_vector_type(2)));
typedef h16 half8 __attribute__((ext_vector_type(8)));
typedef float f32x4 __attribute__((ext_vector_type(4)));

// ---- workspace layout (float units) ----
#define OFF_CNT    0              // int[1024]           (memset to 0 each call)
#define OFF_IDX    1024           // int[1000*1024]
#define OFF_SOFT   1025024        // float[1024*10]
#define OFF_FEATH  1035264        // h16[1024*128]  = 65536 floats
#define OFF_AVEH   1100800        // h16[10000*128] = 640000 floats
#define OFF_CMC    1740800        // float[10000*8] per-cm epilogue constants
// total 1,820,800 floats = 7.28 MB

// ---------------- K1: soft assignment + bucket insert (one wave per sample) --
__global__ __launch_bounds__(256) void k1_soft_assign(
    const float* __restrict__ feat,      // [1024][128]
    const float* __restrict__ ave_old,   // [1000][10][128]
    const int*   __restrict__ labels,    // [1024]
    int*   __restrict__ cnt,             // [1000] zeroed
    int*   __restrict__ idx,             // [1000][1024]
    float* __restrict__ soft,            // [1024][10]
    h16*   __restrict__ feat_h)          // [1024][128]
{
    const int n = blockIdx.x * 4 + (threadIdx.x >> 6);
    const int l = threadIdx.x & 63;
    const int lab = labels[n];

    float2 f = ((const float2*)(feat + n * D_FEAT))[l];
    ((h16x2*)(feat_h + n * D_FEAT))[l] = (h16x2){(h16)f.x, (h16)f.y};

    float fn = f.x * f.x + f.y * f.y;
    #pragma unroll
    for (int s = 1; s < 64; s <<= 1) fn += __shfl_xor(fn, s);
    const float fnorm = sqrtf(fn);

    float sc[M_MODES];
    #pragma unroll
    for (int m = 0; m < M_MODES; ++m) {
        float2 a = ((const float2*)(ave_old + (lab * M_MODES + m) * D_FEAT))[l];
        float d  = f.x * a.x + f.y * a.y;
        float an = a.x * a.x + a.y * a.y;
        #pragma unroll
        for (int s = 1; s < 64; s <<= 1) {
            d  += __shfl_xor(d, s);
            an += __shfl_xor(an, s);
        }
        float den = fmaxf(fnorm * sqrtf(an), 1e-8f);
        sc[m] = d / den;
    }
    float mx = sc[0];
    #pragma unroll
    for (int m = 1; m < M_MODES; ++m) mx = fmaxf(mx, sc[m]);
    float se = 0.f;
    #pragma unroll
    for (int m = 0; m < M_MODES; ++m) { sc[m] = __expf(sc[m] - mx); se += sc[m]; }
    const float inv = 1.0f / se;

    if (l == 0) {
        int pos = atomicAdd(cnt + lab, 1);
        idx[lab * 1024 + pos] = n;
        #pragma unroll
        for (int m = 0; m < M_MODES; ++m) soft[n * M_MODES + m] = sc[m] * inv;
    }
}

// ---------------- K2: gather-side CV update, kappa, epilogue constants -------
// cmc[cm*8+{0..5}] = { 2k, k*k+3970, sw_k, c1, c2, c3 } where sw_k=sqrt(k^2+3969),
// logit(s) = D*(c1 + D*(c2 + D*c3)),  D = (2k*s+1)/(sw_new+sw_k).
__global__ __launch_bounds__(256) void k2_update(
    const float* __restrict__ feat,      // [1024][128]
    const float* __restrict__ ave_old,   // [10000][128]
    const float* __restrict__ amount,    // [10000]
    const int*   __restrict__ cnt,       // [1000]
    const int*   __restrict__ idx,       // [1000][1024]
    const float* __restrict__ soft,      // [1024][10]
    h16*   __restrict__ ave_h,           // [10000][128]
    float* __restrict__ cmc)             // [10000][8]
{
    const int wid = blockIdx.x * 4 + (threadIdx.x >> 6);   // 0..9999
    const int l   = threadIdx.x & 63;
    const int c   = wid / M_MODES;
    const int m   = wid - c * M_MODES;

    const int nc = cnt[c];
    float ssum = 0.f, wx = 0.f, wy = 0.f;
    for (int i = 0; i < nc; ++i) {
        int n = idx[c * 1024 + i];
        float s = soft[n * M_MODES + m];
        float2 f = ((const float2*)(feat + n * D_FEAT))[l];
        ssum += s;
        wx = fmaf(s, f.x, wx);
        wy = fmaf(s, f.y, wy);
    }

    const float am = amount[wid];
    float w = ssum / (ssum + am);
    if (!(w == w)) w = 0.0f;
    const float dn = (ssum == 0.0f) ? 1.0f : ssum;

    float2 ao = ((const float2*)(ave_old + wid * D_FEAT))[l];
    float ax = ao.x * (1.0f - w) + (wx / dn) * w;
    float ay = ao.y * (1.0f - w) + (wy / dn) * w;

    float r2 = ax * ax + ay * ay;
    #pragma unroll
    for (int s2 = 1; s2 < 64; s2 <<= 1) r2 += __shfl_xor(r2, s2);
    const float R = sqrtf(r2);

    float kappa = 128.0f * R / (1.0f - R * R);
    if (kappa > 1e5f || kappa < 0.0f) kappa = 1e5f;

    const float nrm = fmaxf(R, 1e-12f);
    ((h16x2*)(ave_h + wid * D_FEAT))[l] = (h16x2){(h16)(ax / nrm), (h16)(ay / nrm)};

    if (l == 0) {
        float k   = kappa;
        float swk = sqrtf(fmaf(k, k, 3969.0f));
        float i1  = 1.0f / (63.0f + swk);
        float i2  = 1.0f / swk;
        float c1  = 1.0f - 63.0f * i1 - 0.5f * i2;
        float c2  = 31.5f * i1 * i1 + 0.25f * i2 * i2;
        float c3  = -(21.0f * i1 * i1 * i1 + (1.0f / 6.0f) * i2 * i2 * i2);
        float4* p = (float4*)(cmc + wid * 8);
        p[0] = make_float4(2.0f * k, fmaf(k, k, 3970.0f), swk, c1);
        p[1] = make_float4(c2, c3, 0.0f, 0.0f);
    }
}

// ---------------- K3: f16 MFMA sims-GEMM + rational vMF logit + mode-max -----
// block tile: 128 n x 80 cm (8 whole classes); 4 waves x (32n x 80cm);
// LDS: A 128x128h (32KB) + B 80x128h (20KB), XOR-swizzled 16B slots. 52KB.
#define SWZ(row, j) (((row) << 8) + ((((j) ^ ((row) & 15))) << 4))
#define LSTR 81
__global__ __launch_bounds__(256) void k3_logits(
    const h16*   __restrict__ feat_h,    // [1024][128]
    const h16*   __restrict__ ave_h,     // [10000][128]
    const float* __restrict__ cmc,       // [10000][8]
    float* __restrict__ out)             // [1024][1000]
{
    __shared__ __align__(16) char smem[128 * 256 + 80 * 256];  // 53248 B
    char*  smemB = smem + 128 * 256;
    float* ls    = (float*)smem;          // [64][81] overlay (20736 B)

    const int tid    = threadIdx.x;
    const int cmbase = blockIdx.x * 80;   // 125 tiles, exact
    const int nbase  = blockIdx.y * 128;  // 8 tiles, exact

    // stage A: 128 rows x 16 float4 (swizzled 16B slots)
    {
        const float4* src = (const float4*)(feat_h + nbase * D_FEAT);
        #pragma unroll
        for (int i = 0; i < 8; ++i) {
            int e = tid + i * 256;
            int r = e >> 4, j = e & 15;
            *(float4*)(smem + SWZ(r, j)) = src[e];
        }
    }
    // stage B: 80 rows x 16 float4
    {
        const float4* src = (const float4*)(ave_h + cmbase * D_FEAT);
        #pragma unroll
        for (int i = 0; i < 5; ++i) {
            int e = tid + i * 256;
            int r = e >> 4, j = e & 15;
            *(float4*)(smemB + SWZ(r, j)) = src[e];
        }
    }
    __syncthreads();

    const int wave = tid >> 6;
    const int lane = tid & 63;
    const int lrow = lane & 15;
    const int lhi  = lane >> 4;

    f32x4 acc[2][5] = {};
    #pragma unroll
    for (int ks = 0; ks < 4; ++ks) {
        half8 a0 = *(const half8*)(smem  + SWZ(wave * 32 +      lrow, ks * 4 + lhi));
        half8 a1 = *(const half8*)(smem  + SWZ(wave * 32 + 16 + lrow, ks * 4 + lhi));
        #pragma unroll
        for (int t = 0; t < 5; ++t) {
            half8 b = *(const half8*)(smemB + SWZ(t * 16 + lrow, ks * 4 + lhi));
            acc[0][t] = __builtin_amdgcn_mfma_f32_16x16x32_f16(a0, b, acc[0][t], 0, 0, 0);
            acc[1][t] = __builtin_amdgcn_mfma_f32_16x16x32_f16(a1, b, acc[1][t], 0, 0, 0);
        }
    }

    // epilogue: rational vMF logit (no transcendentals beyond sqrt+rcp)
    #pragma unroll
    for (int t = 0; t < 5; ++t) {
        const int cm = cmbase + t * 16 + lrow;
        float4 p0 = ((const float4*)(cmc + cm * 8))[0];  // 2k, k^2+3970, swk, c1
        float4 p1 = ((const float4*)(cmc + cm * 8))[1];  // c2, c3
        #pragma unroll
        for (int h = 0; h < 2; ++h)
            #pragma unroll
            for (int r = 0; r < 4; ++r) {
                float s   = acc[h][t][r];
                float swn = sqrtf(fmaf(p0.x, s, p0.y));
                float num = fmaf(p0.x, s, 1.0f);
                float D   = __fdividef(num, swn + p0.z);
                acc[h][t][r] = D * fmaf(D, fmaf(D, p1.y, p1.x), p0.w);
            }
    }

    // mode-max via two 64-row LDS passes (ls overlays smem)
    #pragma unroll
    for (int p = 0; p < 2; ++p) {
        __syncthreads();   // pass 0: all MFMA LDS reads done; pass 1: prev reduce done
        #pragma unroll
        for (int t = 0; t < 5; ++t)
            #pragma unroll
            for (int r = 0; r < 4; ++r)
                ls[(wave * 16 + lhi * 4 + r) * LSTR + t * 16 + lrow] = acc[p][t][r];
        __syncthreads();
        #pragma unroll
        for (int rep = 0; rep < 2; ++rep) {
            int id = rep * 256 + tid;
            int q  = id >> 3;          // ls row 0..63
            int c  = id & 7;           // class within block
            const float* row = ls + q * LSTR + c * 10;
            float mx = row[0];
            #pragma unroll
            for (int j = 1; j < 10; ++j) mx = fmaxf(mx, row[j]);
            int n = nbase + (q >> 4) * 32 + p * 16 + (q & 15);
            out[n * C_NUM + blockIdx.x * 8 + c] = mx;
        }
    }
}

extern "C" void kernel_launch(void* const* d_in, const int* in_sizes, int n_in,
                              void* d_out, int out_size, void* d_ws, size_t ws_size,
                              hipStream_t stream) {
    const float* feat    = (const float*)d_in[0];
    const float* ave_old = (const float*)d_in[1];
    const float* amount  = (const float*)d_in[2];
    const int*   labels  = (const int*)d_in[3];
    float* out = (float*)d_out;
    float* ws  = (float*)d_ws;

    int*   cnt    = (int*)(ws + OFF_CNT);
    int*   idx    = (int*)(ws + OFF_IDX);
    float* soft   = ws + OFF_SOFT;
    h16*   feat_h = (h16*)(ws + OFF_FEATH);
    h16*   ave_h  = (h16*)(ws + OFF_AVEH);
    float* cmc    = ws + OFF_CMC;

    // A/B probe vs round 6 (identical kernels; {memset,k1,k2} count 1 -> 3):
    // memset+k1+k2 = (R7_dur - R6_dur) / 2, exactly.
    // (k1 needs cnt re-zeroed before each rerun; k2 is pure.)
    for (int rep = 0; rep < 3; ++rep) {
        (void)hipMemsetAsync(cnt, 0, 1024 * sizeof(int), stream);

        k1_soft_assign<<<dim3(N_BATCH / 4), dim3(256), 0, stream>>>(
            feat, ave_old, labels, cnt, idx, soft, feat_h);

        k2_update<<<dim3(CMTOT / 4), dim3(256), 0, stream>>>(
            feat, ave_old, amount, cnt, idx, soft, ave_h, cmc);
    }

    k3_logits<<<dim3(125, 8), dim3(256), 0, stream>>>(
        feat_h, ave_h, cmc, out);
}

// Round 9
// 92.017 us; speedup vs baseline: 1.3292x; 1.3292x over previous
//
#include <hip/hip_runtime.h>
#include <math.h>

#define C_NUM 1000
#define M_MODES 10
#define CMTOT (C_NUM * M_MODES)   // 10000
#define D_FEAT 128
#define N_BATCH 1024

typedef _Float16 h16;
typedef h16 h16x2 __attribute__((ext_vector_type(2)));
typedef h16 half8 __attribute__((ext_vector_type(8)));
typedef float f32x4 __attribute__((ext_vector_type(4)));

// ---- workspace layout (float units) ----
#define OFF_FEATH  0              // h16[1024*128]  = 65536 floats
#define OFF_AVEH   65536          // h16[10000*128] = 640000 floats
#define OFF_CMC    705536         // float[10000*8] per-cm epilogue constants

// ---------------- K2': fused prep (block = one class) ------------------------
// Replaces memset+k1+k2 (3 dispatches -> 1). Each block scans labels to find
// its class's samples (avg ~1), computes their soft mode-assignments locally,
// then the CV update / kappa / cmc constants for its 10 modes.
// Blocks 0..255 additionally convert feat (4 rows each) to fp16 for k3.
// cmc[cm*8+{0..5}] = { 2k, k*k+3970, sw_k, c1, c2, c3 }, sw_k=sqrt(k^2+3969);
// logit(s) = D*(c1 + D*(c2 + D*c3)),  D = (2k*s+1)/(sw_new+sw_k).
__global__ __launch_bounds__(256) void k2_fused(
    const float* __restrict__ feat,      // [1024][128]
    const float* __restrict__ ave_old,   // [1000][10][128]
    const float* __restrict__ amount,    // [10000]
    const int*   __restrict__ labels,    // [1024]
    h16*   __restrict__ feat_h,          // [1024][128]
    h16*   __restrict__ ave_h,           // [10000][128]
    float* __restrict__ cmc)             // [10000][8]
{
    const int c    = blockIdx.x;         // class 0..999
    const int tid  = threadIdx.x;
    const int wave = tid >> 6;
    const int lane = tid & 63;

    __shared__ int   s_cnt;
    __shared__ int   s_list[N_BATCH];        // 4 KB
    __shared__ float s_an[M_MODES];          // ||ave_old[c,m]||
    __shared__ float s_soft[N_BATCH * 10 / 4]; // cap 256 samples/class (10 KB)
    // (test labels are 1024 uniform into 1000 classes: max bucket ~6 << 256)

    const float2* feat2 = (const float2*)feat;
    const float2* ave2  = (const float2*)ave_old;

    // feat -> fp16 (independent side task)
    if (c < 256) {
        const int n = c * 4 + wave;
        float2 f = feat2[n * 64 + lane];
        ((h16x2*)(feat_h + n * D_FEAT))[lane] = (h16x2){(h16)f.x, (h16)f.y};
    }

    if (tid == 0) s_cnt = 0;
    __syncthreads();

    // phase A: find my samples
    for (int n = tid; n < N_BATCH; n += 256)
        if (labels[n] == c) { int p = atomicAdd(&s_cnt, 1); s_list[p] = n; }

    // phase B: prototype norms
    #pragma unroll
    for (int m = wave; m < M_MODES; m += 4) {
        float2 a = ave2[(c * M_MODES + m) * 64 + lane];
        float an = a.x * a.x + a.y * a.y;
        #pragma unroll
        for (int s = 1; s < 64; s <<= 1) an += __shfl_xor(an, s);
        if (lane == 0) s_an[m] = sqrtf(an);
    }
    __syncthreads();

    const int nc = s_cnt < 256 ? s_cnt : 256;

    // phase C: soft assignment for my samples (one wave per sample)
    for (int i = wave; i < nc; i += 4) {
        const int n = s_list[i];
        float2 f = feat2[n * 64 + lane];
        float fn = f.x * f.x + f.y * f.y;
        float d[M_MODES];
        #pragma unroll
        for (int m = 0; m < M_MODES; ++m) {
            float2 a = ave2[(c * M_MODES + m) * 64 + lane];
            d[m] = f.x * a.x + f.y * a.y;
        }
        #pragma unroll
        for (int s = 1; s < 64; s <<= 1) {
            fn += __shfl_xor(fn, s);
            #pragma unroll
            for (int m = 0; m < M_MODES; ++m) d[m] += __shfl_xor(d[m], s);
        }
        const float fnorm = sqrtf(fn);
        float sc[M_MODES], mx = -INFINITY;
        #pragma unroll
        for (int m = 0; m < M_MODES; ++m) {
            float den = fmaxf(fnorm * s_an[m], 1e-8f);
            sc[m] = d[m] / den;
            mx = fmaxf(mx, sc[m]);
        }
        float se = 0.f;
        #pragma unroll
        for (int m = 0; m < M_MODES; ++m) { sc[m] = __expf(sc[m] - mx); se += sc[m]; }
        const float inv = 1.0f / se;
        if (lane == 0) {
            #pragma unroll
            for (int m = 0; m < M_MODES; ++m) s_soft[i * M_MODES + m] = sc[m] * inv;
        }
    }
    __syncthreads();

    // phase D: per-mode CV update + kappa + cmc (one wave per mode, strided)
    for (int m = wave; m < M_MODES; m += 4) {
        const int wid = c * M_MODES + m;
        float ssum = 0.f, wx = 0.f, wy = 0.f;
        for (int i = 0; i < nc; ++i) {
            float s  = s_soft[i * M_MODES + m];
            float2 f = feat2[s_list[i] * 64 + lane];
            ssum += s;
            wx = fmaf(s, f.x, wx);
            wy = fmaf(s, f.y, wy);
        }
        const float am = amount[wid];
        float w = ssum / (ssum + am);
        if (!(w == w)) w = 0.0f;
        const float dn = (ssum == 0.0f) ? 1.0f : ssum;

        float2 ao = ave2[wid * 64 + lane];
        float ax = ao.x * (1.0f - w) + (wx / dn) * w;
        float ay = ao.y * (1.0f - w) + (wy / dn) * w;

        float r2 = ax * ax + ay * ay;
        #pragma unroll
        for (int s2 = 1; s2 < 64; s2 <<= 1) r2 += __shfl_xor(r2, s2);
        const float R = sqrtf(r2);

        float kappa = 128.0f * R / (1.0f - R * R);
        if (kappa > 1e5f || kappa < 0.0f) kappa = 1e5f;

        const float nrm = fmaxf(R, 1e-12f);
        ((h16x2*)(ave_h + wid * D_FEAT))[lane] = (h16x2){(h16)(ax / nrm), (h16)(ay / nrm)};

        if (lane == 0) {
            float k   = kappa;
            float swk = sqrtf(fmaf(k, k, 3969.0f));
            float i1  = 1.0f / (63.0f + swk);
            float i2  = 1.0f / swk;
            float c1  = 1.0f - 63.0f * i1 - 0.5f * i2;
            float c2  = 31.5f * i1 * i1 + 0.25f * i2 * i2;
            float c3  = -(21.0f * i1 * i1 * i1 + (1.0f / 6.0f) * i2 * i2 * i2);
            float4* p = (float4*)(cmc + wid * 8);
            p[0] = make_float4(2.0f * k, fmaf(k, k, 3970.0f), swk, c1);
            p[1] = make_float4(c2, c3, 0.0f, 0.0f);
        }
    }
}

// ---------------- K3: f16 MFMA sims-GEMM + rational vMF logit + mode-max -----
// block tile: 128 n x 80 cm (8 whole classes); 4 waves x (32n x 80cm);
// LDS: A 128x128h (32KB) + B 80x128h (20KB), XOR-swizzled 16B slots. 52KB.
#define SWZ(row, j) (((row) << 8) + ((((j) ^ ((row) & 15))) << 4))
#define LSTR 81
__global__ __launch_bounds__(256) void k3_logits(
    const h16*   __restrict__ feat_h,    // [1024][128]
    const h16*   __restrict__ ave_h,     // [10000][128]
    const float* __restrict__ cmc,       // [10000][8]
    float* __restrict__ out)             // [1024][1000]
{
    __shared__ __align__(16) char smem[128 * 256 + 80 * 256];  // 53248 B
    char*  smemB = smem + 128 * 256;
    float* ls    = (float*)smem;          // [128][81] overlay (41472 B)

    const int tid    = threadIdx.x;
    const int cmbase = blockIdx.x * 80;   // 125 tiles, exact
    const int nbase  = blockIdx.y * 128;  // 8 tiles, exact

    // stage A: 128 rows x 16 float4 (swizzled 16B slots)
    {
        const float4* src = (const float4*)(feat_h + nbase * D_FEAT);
        #pragma unroll
        for (int i = 0; i < 8; ++i) {
            int e = tid + i * 256;
            int r = e >> 4, j = e & 15;
            *(float4*)(smem + SWZ(r, j)) = src[e];
        }
    }
    // stage B: 80 rows x 16 float4
    {
        const float4* src = (const float4*)(ave_h + cmbase * D_FEAT);
        #pragma unroll
        for (int i = 0; i < 5; ++i) {
            int e = tid + i * 256;
            int r = e >> 4, j = e & 15;
            *(float4*)(smemB + SWZ(r, j)) = src[e];
        }
    }
    __syncthreads();

    const int wave = tid >> 6;
    const int lane = tid & 63;
    const int lrow = lane & 15;
    const int lhi  = lane >> 4;

    f32x4 acc[2][5] = {};
    #pragma unroll
    for (int ks = 0; ks < 4; ++ks) {
        half8 a0 = *(const half8*)(smem  + SWZ(wave * 32 +      lrow, ks * 4 + lhi));
        half8 a1 = *(const half8*)(smem  + SWZ(wave * 32 + 16 + lrow, ks * 4 + lhi));
        #pragma unroll
        for (int t = 0; t < 5; ++t) {
            half8 b = *(const half8*)(smemB + SWZ(t * 16 + lrow, ks * 4 + lhi));
            acc[0][t] = __builtin_amdgcn_mfma_f32_16x16x32_f16(a0, b, acc[0][t], 0, 0, 0);
            acc[1][t] = __builtin_amdgcn_mfma_f32_16x16x32_f16(a1, b, acc[1][t], 0, 0, 0);
        }
    }

    // epilogue: rational vMF logit (register-only; no LDS)
    #pragma unroll
    for (int t = 0; t < 5; ++t) {
        const int cm = cmbase + t * 16 + lrow;
        float4 p0 = ((const float4*)(cmc + cm * 8))[0];  // 2k, k^2+3970, swk, c1
        float4 p1 = ((const float4*)(cmc + cm * 8))[1];  // c2, c3
        #pragma unroll
        for (int h = 0; h < 2; ++h)
            #pragma unroll
            for (int r = 0; r < 4; ++r) {
                float s   = acc[h][t][r];
                float swn = sqrtf(fmaf(p0.x, s, p0.y));
                float num = fmaf(p0.x, s, 1.0f);
                float D   = __fdividef(num, swn + p0.z);
                acc[h][t][r] = D * fmaf(D, fmaf(D, p1.y, p1.x), p0.w);
            }
    }

    // single-pass mode-max: ls[128][81] overlay, 2 barriers total
    __syncthreads();   // all waves done with aT/bT LDS reads
    #pragma unroll
    for (int t = 0; t < 5; ++t)
        #pragma unroll
        for (int h = 0; h < 2; ++h)
            #pragma unroll
            for (int r = 0; r < 4; ++r)
                ls[(wave * 32 + h * 16 + lhi * 4 + r) * LSTR + t * 16 + lrow]
                    = acc[h][t][r];
    __syncthreads();

    // 128 rows x 8 classes = 1024 outputs; 4 per thread
    #pragma unroll
    for (int rep = 0; rep < 4; ++rep) {
        int id = rep * 256 + tid;
        int q  = id >> 3;              // n-local 0..127
        int cl = id & 7;               // class within block
        const float* row = ls + q * LSTR + cl * 10;
        float mx = row[0];
        #pragma unroll
        for (int j = 1; j < 10; ++j) mx = fmaxf(mx, row[j]);
        out[(nbase + q) * C_NUM + blockIdx.x * 8 + cl] = mx;
    }
}

extern "C" void kernel_launch(void* const* d_in, const int* in_sizes, int n_in,
                              void* d_out, int out_size, void* d_ws, size_t ws_size,
                              hipStream_t stream) {
    const float* feat    = (const float*)d_in[0];
    const float* ave_old = (const float*)d_in[1];
    const float* amount  = (const float*)d_in[2];
    const int*   labels  = (const int*)d_in[3];
    float* out = (float*)d_out;
    float* ws  = (float*)d_ws;

    h16*   feat_h = (h16*)(ws + OFF_FEATH);
    h16*   ave_h  = (h16*)(ws + OFF_AVEH);
    float* cmc    = ws + OFF_CMC;

    // 2 dispatches total (was 4): fused prep, then GEMM+epilogue.
    k2_fused<<<dim3(C_NUM), dim3(256), 0, stream>>>(
        feat, ave_old, amount, labels, feat_h, ave_h, cmc);

    k3_logits<<<dim3(125, 8), dim3(256), 0, stream>>>(
        feat_h, ave_h, cmc, out);
}

// Round 10
// 90.017 us; speedup vs baseline: 1.3587x; 1.0222x over previous
//
#include <hip/hip_runtime.h>
#include <math.h>

#define C_NUM 1000
#define M_MODES 10
#define CMTOT (C_NUM * M_MODES)   // 10000
#define D_FEAT 128
#define N_BATCH 1024

typedef _Float16 h16;
typedef h16 h16x2 __attribute__((ext_vector_type(2)));
typedef h16 half8 __attribute__((ext_vector_type(8)));
typedef float f32x4 __attribute__((ext_vector_type(4)));

// ---- workspace layout (float units) ----
#define OFF_FEATH  0              // h16[1024*128]  = 65536 floats
#define OFF_AVEH   65536          // h16[10000*128] = 640000 floats
#define OFF_CMC    705536         // float[10000*8] per-cm epilogue constants

// ---------------- K2': fused prep (block = one class) ------------------------
// (byte-identical to round 9 — this round's single variable is k3's block size)
__global__ __launch_bounds__(256) void k2_fused(
    const float* __restrict__ feat,      // [1024][128]
    const float* __restrict__ ave_old,   // [1000][10][128]
    const float* __restrict__ amount,    // [10000]
    const int*   __restrict__ labels,    // [1024]
    h16*   __restrict__ feat_h,          // [1024][128]
    h16*   __restrict__ ave_h,           // [10000][128]
    float* __restrict__ cmc)             // [10000][8]
{
    const int c    = blockIdx.x;         // class 0..999
    const int tid  = threadIdx.x;
    const int wave = tid >> 6;
    const int lane = tid & 63;

    __shared__ int   s_cnt;
    __shared__ int   s_list[N_BATCH];        // 4 KB
    __shared__ float s_an[M_MODES];          // ||ave_old[c,m]||
    __shared__ float s_soft[N_BATCH * 10 / 4]; // cap 256 samples/class (10 KB)

    const float2* feat2 = (const float2*)feat;
    const float2* ave2  = (const float2*)ave_old;

    // feat -> fp16 (independent side task)
    if (c < 256) {
        const int n = c * 4 + wave;
        float2 f = feat2[n * 64 + lane];
        ((h16x2*)(feat_h + n * D_FEAT))[lane] = (h16x2){(h16)f.x, (h16)f.y};
    }

    if (tid == 0) s_cnt = 0;
    __syncthreads();

    // phase A: find my samples
    for (int n = tid; n < N_BATCH; n += 256)
        if (labels[n] == c) { int p = atomicAdd(&s_cnt, 1); s_list[p] = n; }

    // phase B: prototype norms
    #pragma unroll
    for (int m = wave; m < M_MODES; m += 4) {
        float2 a = ave2[(c * M_MODES + m) * 64 + lane];
        float an = a.x * a.x + a.y * a.y;
        #pragma unroll
        for (int s = 1; s < 64; s <<= 1) an += __shfl_xor(an, s);
        if (lane == 0) s_an[m] = sqrtf(an);
    }
    __syncthreads();

    const int nc = s_cnt < 256 ? s_cnt : 256;

    // phase C: soft assignment for my samples (one wave per sample)
    for (int i = wave; i < nc; i += 4) {
        const int n = s_list[i];
        float2 f = feat2[n * 64 + lane];
        float fn = f.x * f.x + f.y * f.y;
        float d[M_MODES];
        #pragma unroll
        for (int m = 0; m < M_MODES; ++m) {
            float2 a = ave2[(c * M_MODES + m) * 64 + lane];
            d[m] = f.x * a.x + f.y * a.y;
        }
        #pragma unroll
        for (int s = 1; s < 64; s <<= 1) {
            fn += __shfl_xor(fn, s);
            #pragma unroll
            for (int m = 0; m < M_MODES; ++m) d[m] += __shfl_xor(d[m], s);
        }
        const float fnorm = sqrtf(fn);
        float sc[M_MODES], mx = -INFINITY;
        #pragma unroll
        for (int m = 0; m < M_MODES; ++m) {
            float den = fmaxf(fnorm * s_an[m], 1e-8f);
            sc[m] = d[m] / den;
            mx = fmaxf(mx, sc[m]);
        }
        float se = 0.f;
        #pragma unroll
        for (int m = 0; m < M_MODES; ++m) { sc[m] = __expf(sc[m] - mx); se += sc[m]; }
        const float inv = 1.0f / se;
        if (lane == 0) {
            #pragma unroll
            for (int m = 0; m < M_MODES; ++m) s_soft[i * M_MODES + m] = sc[m] * inv;
        }
    }
    __syncthreads();

    // phase D: per-mode CV update + kappa + cmc (one wave per mode, strided)
    for (int m = wave; m < M_MODES; m += 4) {
        const int wid = c * M_MODES + m;
        float ssum = 0.f, wx = 0.f, wy = 0.f;
        for (int i = 0; i < nc; ++i) {
            float s  = s_soft[i * M_MODES + m];
            float2 f = feat2[s_list[i] * 64 + lane];
            ssum += s;
            wx = fmaf(s, f.x, wx);
            wy = fmaf(s, f.y, wy);
        }
        const float am = amount[wid];
        float w = ssum / (ssum + am);
        if (!(w == w)) w = 0.0f;
        const float dn = (ssum == 0.0f) ? 1.0f : ssum;

        float2 ao = ave2[wid * 64 + lane];
        float ax = ao.x * (1.0f - w) + (wx / dn) * w;
        float ay = ao.y * (1.0f - w) + (wy / dn) * w;

        float r2 = ax * ax + ay * ay;
        #pragma unroll
        for (int s2 = 1; s2 < 64; s2 <<= 1) r2 += __shfl_xor(r2, s2);
        const float R = sqrtf(r2);

        float kappa = 128.0f * R / (1.0f - R * R);
        if (kappa > 1e5f || kappa < 0.0f) kappa = 1e5f;

        const float nrm = fmaxf(R, 1e-12f);
        ((h16x2*)(ave_h + wid * D_FEAT))[lane] = (h16x2){(h16)(ax / nrm), (h16)(ay / nrm)};

        if (lane == 0) {
            float k   = kappa;
            float swk = sqrtf(fmaf(k, k, 3969.0f));
            float i1  = 1.0f / (63.0f + swk);
            float i2  = 1.0f / swk;
            float c1  = 1.0f - 63.0f * i1 - 0.5f * i2;
            float c2  = 31.5f * i1 * i1 + 0.25f * i2 * i2;
            float c3  = -(21.0f * i1 * i1 * i1 + (1.0f / 6.0f) * i2 * i2 * i2);
            float4* p = (float4*)(cmc + wid * 8);
            p[0] = make_float4(2.0f * k, fmaf(k, k, 3970.0f), swk, c1);
            p[1] = make_float4(c2, c3, 0.0f, 0.0f);
        }
    }
}

// ---------------- K3: f16 MFMA sims-GEMM + rational vMF logit + mode-max -----
// block tile: 128 n x 80 cm (8 whole classes); NOW 8 waves (512 thr), each
// owning 16 n-rows -> half the per-block serial latency of round 9.
// LDS: A 128x128h (32KB) + B 80x128h (20KB), XOR-swizzled 16B slots. 52KB.
#define SWZ(row, j) (((row) << 8) + ((((j) ^ ((row) & 15))) << 4))
#define LSTR 81
__global__ __launch_bounds__(512) void k3_logits(
    const h16*   __restrict__ feat_h,    // [1024][128]
    const h16*   __restrict__ ave_h,     // [10000][128]
    const float* __restrict__ cmc,       // [10000][8]
    float* __restrict__ out)             // [1024][1000]
{
    __shared__ __align__(16) char smem[128 * 256 + 80 * 256];  // 53248 B
    char*  smemB = smem + 128 * 256;
    float* ls    = (float*)smem;          // [128][81] overlay (41472 B)

    const int tid    = threadIdx.x;
    const int cmbase = blockIdx.x * 80;   // 125 tiles, exact
    const int nbase  = blockIdx.y * 128;  // 8 tiles, exact

    // stage A: 128 rows x 16 float4 (swizzled 16B slots), 4 per thread
    {
        const float4* src = (const float4*)(feat_h + nbase * D_FEAT);
        #pragma unroll
        for (int i = 0; i < 4; ++i) {
            int e = tid + i * 512;
            int r = e >> 4, j = e & 15;
            *(float4*)(smem + SWZ(r, j)) = src[e];
        }
    }
    // stage B: 80 rows x 16 float4 = 1280
    for (int e = tid; e < 1280; e += 512) {
        int r = e >> 4, j = e & 15;
        *(float4*)(smemB + SWZ(r, j)) = ((const float4*)(ave_h + cmbase * D_FEAT))[e];
    }
    __syncthreads();

    const int wave = tid >> 6;    // 0..7 -> n-rows wave*16..wave*16+15
    const int lane = tid & 63;
    const int lrow = lane & 15;
    const int lhi  = lane >> 4;

    f32x4 acc[5] = {};
    #pragma unroll
    for (int ks = 0; ks < 4; ++ks) {
        half8 a = *(const half8*)(smem + SWZ(wave * 16 + lrow, ks * 4 + lhi));
        #pragma unroll
        for (int t = 0; t < 5; ++t) {
            half8 b = *(const half8*)(smemB + SWZ(t * 16 + lrow, ks * 4 + lhi));
            acc[t] = __builtin_amdgcn_mfma_f32_16x16x32_f16(a, b, acc[t], 0, 0, 0);
        }
    }

    // epilogue: rational vMF logit (register-only; no LDS)
    #pragma unroll
    for (int t = 0; t < 5; ++t) {
        const int cm = cmbase + t * 16 + lrow;
        float4 p0 = ((const float4*)(cmc + cm * 8))[0];  // 2k, k^2+3970, swk, c1
        float4 p1 = ((const float4*)(cmc + cm * 8))[1];  // c2, c3
        #pragma unroll
        for (int r = 0; r < 4; ++r) {
            float s   = acc[t][r];
            float swn = sqrtf(fmaf(p0.x, s, p0.y));
            float num = fmaf(p0.x, s, 1.0f);
            float D   = __fdividef(num, swn + p0.z);
            acc[t][r] = D * fmaf(D, fmaf(D, p1.y, p1.x), p0.w);
        }
    }

    // single-pass mode-max: ls[128][81] overlay, 2 barriers
    __syncthreads();   // all waves done with aT/bT LDS reads
    #pragma unroll
    for (int t = 0; t < 5; ++t)
        #pragma unroll
        for (int r = 0; r < 4; ++r)
            ls[(wave * 16 + lhi * 4 + r) * LSTR + t * 16 + lrow] = acc[t][r];
    __syncthreads();

    // 128 rows x 8 classes = 1024 outputs; 2 per thread
    #pragma unroll
    for (int rep = 0; rep < 2; ++rep) {
        int id = rep * 512 + tid;
        int q  = id >> 3;              // n-local 0..127
        int cl = id & 7;               // class within block
        const float* row = ls + q * LSTR + cl * 10;
        float mx = row[0];
        #pragma unroll
        for (int j = 1; j < 10; ++j) mx = fmaxf(mx, row[j]);
        out[(nbase + q) * C_NUM + blockIdx.x * 8 + cl] = mx;
    }
}

extern "C" void kernel_launch(void* const* d_in, const int* in_sizes, int n_in,
                              void* d_out, int out_size, void* d_ws, size_t ws_size,
                              hipStream_t stream) {
    const float* feat    = (const float*)d_in[0];
    const float* ave_old = (const float*)d_in[1];
    const float* amount  = (const float*)d_in[2];
    const int*   labels  = (const int*)d_in[3];
    float* out = (float*)d_out;
    float* ws  = (float*)d_ws;

    h16*   feat_h = (h16*)(ws + OFF_FEATH);
    h16*   ave_h  = (h16*)(ws + OFF_AVEH);
    float* cmc    = ws + OFF_CMC;

    k2_fused<<<dim3(C_NUM), dim3(256), 0, stream>>>(
        feat, ave_old, amount, labels, feat_h, ave_h, cmc);

    k3_logits<<<dim3(125, 8), dim3(512), 0, stream>>>(
        feat_h, ave_h, cmc, out);
}